// Round 6
// baseline (94.372 us; speedup 1.0000x reference)
//
#include <hip/hip_runtime.h>
#include <math.h>

#define CIN    16
#define COUT   64
#define H      256
#define W      256
#define OH     254
#define OW     254
#define NTAP   9
#define RING   6
#define STRIP  32

typedef _Float16 f16x8  __attribute__((ext_vector_type(8)));
typedef float    f32x16 __attribute__((ext_vector_type(16)));

// Conflict-tolerant bijective slot map (bits>=3 of slot recover w>=2 -> unxor).
#define XSLOT(w, g) ((((w) << 1) | (g)) ^ (((w) >> 2) & 7))

// weight pack: [tap 9][msub 2][lane 64][e 8] fp16; co=(l&31)+32m, cin=8*(l>>5)+e
__global__ void wpack_kernel(const float* __restrict__ w, _Float16* __restrict__ wpk) {
    int idx = blockIdx.x * 256 + threadIdx.x;   // 0..9215
    if (idx >= NTAP * 2 * 64 * 8) return;
    int e = idx & 7, l = (idx >> 3) & 63, m = (idx >> 9) & 1, t = idx >> 10;
    int co  = (l & 31) + 32 * m;
    int cin = 8 * (l >> 5) + e;
    wpk[idx] = (_Float16)w[((co * CIN + cin) * 3 + t / 3) * 3 + (t % 3)];
}

__device__ __forceinline__ float tanh_fast(float v) {
    float e = __expf(2.0f * v);
    return 1.0f - 2.0f * __builtin_amdgcn_rcpf(e + 1.0f);
}

// 256 threads = 4 waves; block = 32-row strip; 2 independent blocks/CU.
// wave: ph = wave*64 px; per iteration computes 1 output row (n=0..1).
__global__ __launch_bounds__(256, 2) void conv_mfma_kernel(
        const float* __restrict__ x, const f16x8* __restrict__ wpk,
        const float* __restrict__ bias, float* __restrict__ out) {
    __shared__ f16x8 xs[RING * 512];            // 48 KiB: 6-row ring

    const int tid = threadIdx.x;
    const int b   = blockIdx.x >> 3;            // image
    const int s   = blockIdx.x & 7;             // 32-row strip
    const int oh0 = s * STRIP;

    const float* xb = x + (size_t)b * CIN * H * W;
    const int lane = tid & 63;

    // ---- weights: global -> 72 VGPRs (loop-invariant) ----
    f16x8 wreg[NTAP][2];
#pragma unroll
    for (int t = 0; t < NTAP; ++t)
#pragma unroll
        for (int m = 0; m < 2; ++m)
            wreg[t][m] = wpk[(t * 2 + m) * 64 + lane];

    const int wave = tid >> 6;
    const int ph   = wave * 64;
    const int l31  = lane & 31;
    const int g2   = lane >> 5;

    // bias as an MFMA C-fragment: col=l31(px), row=(r&3)+8*(r>>2)+4*g2+32m (co)
    f32x16 cbias[2];
#pragma unroll
    for (int m = 0; m < 2; ++m)
#pragma unroll
        for (int r = 0; r < 16; ++r)
            cbias[m][r] = bias[(r & 3) + 8 * (r >> 2) + 4 * g2 + 32 * m];

    // fragment slot offsets (loop-invariant)
    int off[3][2];
#pragma unroll
    for (int kw = 0; kw < 3; ++kw)
#pragma unroll
        for (int n = 0; n < 2; ++n) {
            int w = ph + 32 * n + l31 + kw;
            if (w > 255) w = 255;
            off[kw][n] = XSLOT(w, g2);
        }

    // staging: thread t owns px=t, all 16 cin of one row
#define STAGE_LOAD(rowAbs, v)                                                   \
    {                                                                           \
        int row_ = (rowAbs) > 255 ? 255 : (rowAbs);                             \
        const float* p_ = xb + (size_t)row_ * W + tid;                          \
        _Pragma("unroll")                                                       \
        for (int c = 0; c < CIN; ++c) v[c] = p_[(size_t)c * (H * W)];           \
    }
#define STAGE_WRITE(slot, v)                                                    \
    {                                                                           \
        f16x8 q0, q1;                                                           \
        _Pragma("unroll")                                                       \
        for (int c = 0; c < 8; ++c) { q0[c] = (_Float16)v[c];                   \
                                      q1[c] = (_Float16)v[c + 8]; }             \
        xs[(slot) * 512 + XSLOT(tid, 0)] = q0;                                  \
        xs[(slot) * 512 + XSLOT(tid, 1)] = q1;                                  \
    }

    // prologue: rows oh0..oh0+3 -> slots 0..3
#pragma unroll
    for (int i = 0; i < 4; ++i) {
        float v[CIN];
        STAGE_LOAD(oh0 + i, v)
        STAGE_WRITE(i, v)
    }
    __syncthreads();

    int rs0 = 0, rs1 = 1, rs2 = 2, wsl = 4;     // ring cursors: r, r+1, r+2, r+4

    for (int r = 0; r < STRIP; ++r) {
        // T14 issue-early: global loads for input row r+4
        float v[CIN];
        STAGE_LOAD(oh0 + r + 4, v)

        const f16x8* x0 = xs + rs0 * 512;
        const f16x8* x1 = xs + rs1 * 512;
        const f16x8* x2 = xs + rs2 * 512;

        f32x16 acc[2][2];
#pragma unroll
        for (int t = 0; t < NTAP; ++t) {
            const int kh = t / 3, kw = t % 3;
            const f16x8* xr = (kh == 0) ? x0 : (kh == 1) ? x1 : x2;
#pragma unroll
            for (int n = 0; n < 2; ++n) {
                f16x8 bf = xr[off[kw][n]];
                if (t == 0) {
                    acc[0][n] = __builtin_amdgcn_mfma_f32_32x32x16_f16(wreg[0][0], bf, cbias[0], 0, 0, 0);
                    acc[1][n] = __builtin_amdgcn_mfma_f32_32x32x16_f16(wreg[0][1], bf, cbias[1], 0, 0, 0);
                } else {
                    acc[0][n] = __builtin_amdgcn_mfma_f32_32x32x16_f16(wreg[t][0], bf, acc[0][n], 0, 0, 0);
                    acc[1][n] = __builtin_amdgcn_mfma_f32_32x32x16_f16(wreg[t][1], bf, acc[1][n], 0, 0, 0);
                }
            }
        }

        // epilogue: min over 64 cout -> tanh(tanh) -> store
        const int oh = oh0 + r;
#pragma unroll
        for (int n = 0; n < 2; ++n) {
            float mn = fminf(acc[0][n][0], acc[1][n][0]);
#pragma unroll
            for (int q = 1; q < 16; ++q)
                mn = fminf(mn, fminf(acc[0][n][q], acc[1][n][q]));
            mn = fminf(mn, __shfl_xor(mn, 32));
            float t2 = tanh_fast(tanh_fast(mn));
            int px = ph + 32 * n + l31;
            if (g2 == 0 && px < OW && oh < OH)
                out[((size_t)b * OH + oh) * OW + px] = t2;
        }

        // write-late: row r+4 -> ring slot (r+4)%RING
        STAGE_WRITE(wsl, v)

        if (r & 1) __syncthreads();

        rs0 = (rs0 == RING - 1) ? 0 : rs0 + 1;
        rs1 = (rs1 == RING - 1) ? 0 : rs1 + 1;
        rs2 = (rs2 == RING - 1) ? 0 : rs2 + 1;
        wsl = (wsl == RING - 1) ? 0 : wsl + 1;
    }
}

extern "C" void kernel_launch(void* const* d_in, const int* in_sizes, int n_in,
                              void* d_out, int out_size, void* d_ws, size_t ws_size,
                              hipStream_t stream) {
    const float* x    = (const float*)d_in[0];
    const float* w    = (const float*)d_in[1];
    const float* bias = (const float*)d_in[2];
    float* out = (float*)d_out;
    _Float16* wpk = (_Float16*)d_ws;   // 9216 fp16 = 18,432 B

    wpack_kernel<<<36, 256, 0, stream>>>(w, wpk);
    conv_mfma_kernel<<<64 * 8, 256, 0, stream>>>(x, (const f16x8*)wpk, bias, out);
}

// Round 7
// 92.731 us; speedup vs baseline: 1.0177x; 1.0177x over previous
//
#include <hip/hip_runtime.h>
#include <math.h>

#define CIN    16
#define COUT   64
#define H      256
#define W      256
#define OH     254
#define OW     254
#define NTAP   9
#define RING   8
#define STRIP  32

typedef _Float16 f16x8  __attribute__((ext_vector_type(8)));
typedef float    f32x16 __attribute__((ext_vector_type(16)));

// Bijective, balanced slot map: reads & writes spread 8 lanes/bank-group.
#define XSLOT(w, g) ((((w) << 1) | (g)) ^ (((w) >> 2) & 7))

// weight pack: [tap 9][msub 2][lane 64][e 8] fp16; co=(l&31)+32m, cin=8*(l>>5)+e
__global__ void wpack_kernel(const float* __restrict__ w, _Float16* __restrict__ wpk) {
    int idx = blockIdx.x * 256 + threadIdx.x;   // 0..9215
    if (idx >= NTAP * 2 * 64 * 8) return;
    int e = idx & 7, l = (idx >> 3) & 63, m = (idx >> 9) & 1, t = idx >> 10;
    int co  = (l & 31) + 32 * m;
    int cin = 8 * (l >> 5) + e;
    wpk[idx] = (_Float16)w[((co * CIN + cin) * 3 + t / 3) * 3 + (t % 3)];
}

__device__ __forceinline__ float tanh_fast(float v) {
    float e = __expf(2.0f * v);
    return 1.0f - 2.0f * __builtin_amdgcn_rcpf(e + 1.0f);
}

// 256 threads = 4 waves; block = 32-row strip; 2 blocks/CU (grid 512).
// Depth-2 software pipeline: loads for row r+6 issued at iter r, consumed
// (LDS-written) at iter r+2 via counted vmcnt — never a full drain.
__global__ __launch_bounds__(256, 2) void conv_mfma_kernel(
        const float* __restrict__ x, const f16x8* __restrict__ wpk,
        const float* __restrict__ bias, float* __restrict__ out) {
    __shared__ f16x8 xs[RING * 512];            // 64 KiB: 8-row ring

    const int tid = threadIdx.x;
    const int b   = blockIdx.x >> 3;            // image
    const int s   = blockIdx.x & 7;             // 32-row strip
    const int oh0 = s * STRIP;

    const float* xb = x + (size_t)b * CIN * H * W;
    const int lane = tid & 63;

    // ---- weights: global -> 72 VGPRs (loop-invariant) ----
    f16x8 wreg[NTAP][2];
#pragma unroll
    for (int t = 0; t < NTAP; ++t)
#pragma unroll
        for (int m = 0; m < 2; ++m)
            wreg[t][m] = wpk[(t * 2 + m) * 64 + lane];

    const int wave = tid >> 6;
    const int ph   = wave * 64;
    const int l31  = lane & 31;
    const int g2   = lane >> 5;

    // bias as an MFMA C-fragment: col=l31(px), row=(r&3)+8*(r>>2)+4*g2+32m (co)
    f32x16 cbias[2];
#pragma unroll
    for (int m = 0; m < 2; ++m)
#pragma unroll
        for (int r = 0; r < 16; ++r)
            cbias[m][r] = bias[(r & 3) + 8 * (r >> 2) + 4 * g2 + 32 * m];

    // fragment slot offsets (loop-invariant)
    int off[3][2];
#pragma unroll
    for (int kw = 0; kw < 3; ++kw)
#pragma unroll
        for (int n = 0; n < 2; ++n) {
            int w = ph + 32 * n + l31 + kw;
            if (w > 255) w = 255;
            off[kw][n] = XSLOT(w, g2);
        }

    // staging mapping: thread = [g 1][pp 7]; loads float2 (2 px) x 8 cin
    const int gld = tid >> 7;                   // cin half
    const int w2  = (tid & 127) * 2;            // pixel pair base

#define STAGE_LOAD(rowAbs, v)                                                   \
    {                                                                           \
        int row_ = (rowAbs) > 255 ? 255 : (rowAbs);                             \
        const float* p_ = xb + (size_t)row_ * W + w2;                           \
        _Pragma("unroll")                                                       \
        for (int c = 0; c < 8; ++c)                                             \
            v[c] = *(const float2*)(p_ + (size_t)(8 * gld + c) * (H * W));      \
    }
#define STAGE_WRITE(slot, v)                                                    \
    {                                                                           \
        f16x8 q0, q1;                                                           \
        _Pragma("unroll")                                                       \
        for (int c = 0; c < 8; ++c) { q0[c] = (_Float16)v[c].x;                 \
                                      q1[c] = (_Float16)v[c].y; }               \
        xs[(slot) * 512 + XSLOT(w2,     gld)] = q0;                             \
        xs[(slot) * 512 + XSLOT(w2 + 1, gld)] = q1;                             \
    }

    // ---- prologue: rows 0..3 -> slots 0..3; issue rows 4,5 in flight ----
    {
        float2 v0[8], v1[8], v2[8], v3[8];
        STAGE_LOAD(oh0 + 0, v0)
        STAGE_LOAD(oh0 + 1, v1)
        STAGE_LOAD(oh0 + 2, v2)
        STAGE_LOAD(oh0 + 3, v3)
        STAGE_WRITE(0, v0)
        STAGE_WRITE(1, v1)
        STAGE_WRITE(2, v2)
        STAGE_WRITE(3, v3)
    }
    float2 vvA[8], vvB[8];
    STAGE_LOAD(oh0 + 4, vvA)
    STAGE_LOAD(oh0 + 5, vvB)
    __syncthreads();

    // ---- one pipeline iteration (r = row within strip, vv = parity set) ----
#define ITER(r, vv)                                                             \
    {                                                                           \
        if ((r) + 4 <= STRIP + 1) STAGE_WRITE(((r) + 4) & 7, vv)                \
        if ((r) + 6 <= STRIP + 1) STAGE_LOAD(oh0 + (r) + 6, vv)                 \
        const f16x8* x0 = xs + (((r)    ) & 7) * 512;                           \
        const f16x8* x1 = xs + (((r) + 1) & 7) * 512;                           \
        const f16x8* x2 = xs + (((r) + 2) & 7) * 512;                           \
        f32x16 acc[2][2];                                                       \
        _Pragma("unroll")                                                       \
        for (int t = 0; t < NTAP; ++t) {                                        \
            const int kh = t / 3, kw = t % 3;                                   \
            const f16x8* xr = (kh == 0) ? x0 : (kh == 1) ? x1 : x2;             \
            _Pragma("unroll")                                                   \
            for (int n = 0; n < 2; ++n) {                                       \
                f16x8 bf = xr[off[kw][n]];                                      \
                if (t == 0) {                                                   \
                    acc[0][n] = __builtin_amdgcn_mfma_f32_32x32x16_f16(wreg[0][0], bf, cbias[0], 0, 0, 0); \
                    acc[1][n] = __builtin_amdgcn_mfma_f32_32x32x16_f16(wreg[0][1], bf, cbias[1], 0, 0, 0); \
                } else {                                                        \
                    acc[0][n] = __builtin_amdgcn_mfma_f32_32x32x16_f16(wreg[t][0], bf, acc[0][n], 0, 0, 0); \
                    acc[1][n] = __builtin_amdgcn_mfma_f32_32x32x16_f16(wreg[t][1], bf, acc[1][n], 0, 0, 0); \
                }                                                               \
            }                                                                   \
        }                                                                       \
        const int oh = oh0 + (r);                                               \
        _Pragma("unroll")                                                       \
        for (int n = 0; n < 2; ++n) {                                           \
            float mn = fminf(acc[0][n][0], acc[1][n][0]);                       \
            _Pragma("unroll")                                                   \
            for (int q = 1; q < 16; ++q)                                        \
                mn = fminf(mn, fminf(acc[0][n][q], acc[1][n][q]));              \
            mn = fminf(mn, __shfl_xor(mn, 32));                                 \
            float t2 = tanh_fast(tanh_fast(mn));                                \
            int px = ph + 32 * n + l31;                                         \
            if (g2 == 0 && px < OW && oh < OH)                                  \
                out[((size_t)b * OH + oh) * OW + px] = t2;                      \
        }                                                                       \
    }

    for (int rr = 0; rr < STRIP; rr += 2) {
        ITER(rr,     vvA)
        ITER(rr + 1, vvB)
        __syncthreads();
    }
}

extern "C" void kernel_launch(void* const* d_in, const int* in_sizes, int n_in,
                              void* d_out, int out_size, void* d_ws, size_t ws_size,
                              hipStream_t stream) {
    const float* x    = (const float*)d_in[0];
    const float* w    = (const float*)d_in[1];
    const float* bias = (const float*)d_in[2];
    float* out = (float*)d_out;
    _Float16* wpk = (_Float16*)d_ws;   // 9216 fp16 = 18,432 B

    wpack_kernel<<<36, 256, 0, stream>>>(w, wpk);
    conv_mfma_kernel<<<64 * 8, 256, 0, stream>>>(x, (const f16x8*)wpk, bias, out);
}